// Round 5
// baseline (1048.050 us; speedup 1.0000x reference)
//
#include <hip/hip_runtime.h>
#include <hip/hip_bf16.h>
#include <math.h>

#define GN 19            // graph nodes
#define BB 256
#define TT 256

typedef short short8 __attribute__((ext_vector_type(8)));
typedef float f4 __attribute__((ext_vector_type(4)));

union Frag { int i[4]; short8 s; };

// wave-local LDS ordering fence: wait LDS ops, NO vmcnt drain, no barrier.
#define LWAIT() __asm__ volatile("s_waitcnt lgkmcnt(0)" ::: "memory")
// workgroup barrier WITHOUT vmcnt(0) drain: global loads/stores stay in flight.
#define WGBAR() __asm__ volatile("s_waitcnt lgkmcnt(0)\ns_barrier" ::: "memory")

// packed RNE float pair -> bf16 pair (v_cvt_pk_bf16_f32 on gfx950)
__device__ __forceinline__ int pkbf(float a, float b) {
    __hip_bfloat162 h2 = __float22bfloat162_rn(make_float2(a, b));
    union { __hip_bfloat162 h; int i; } u; u.h = h2; return u.i;
}

__device__ __forceinline__ float rl(float v, int j) {
    return __int_as_float(__builtin_amdgcn_readlane(__float_as_int(v), j));
}
__device__ __forceinline__ float fexp2(float x) { return __builtin_amdgcn_exp2f(x); }
__device__ __forceinline__ float frcp(float x)  { return __builtin_amdgcn_rcpf(x); }
__device__ __forceinline__ float sigm(float x)  { return frcp(1.f + fexp2(-1.4426950408889634f * x)); }
__device__ __forceinline__ float tanha(float x) { float e = fexp2(2.8853900817779268f * x); return 1.f - 2.f * frcp(e + 1.f); }

// ---------------------------------------------------------------------------
// Kernel A: graph encoder via bf16 MFMA (16x16x32).  One wave per block,
// grid-stride over graphs.  1-wave workgroup => no s_barrier needed at all;
// phase ordering via lgkmcnt waits only (global loads stay in flight).
// Next graph's A is register-prefetched during the current graph's pipeline.
// ---------------------------------------------------------------------------
__global__ __launch_bounds__(64) void encoder_mfma(
    const float* __restrict__ conn,   // (G,19,19)
    const int*   __restrict__ mask,   // (G)
    const float* __restrict__ w1_w,   // (64,19)
    const float* __restrict__ w1_b,   // (64)
    const float* __restrict__ w2_w,   // (64,64)
    const float* __restrict__ w2_b,   // (64)
    float* __restrict__ emb,          // (G,64)
    int num_graphs)
{
    __shared__ float S[2304];         // 9216 B, reused 4 ways
    __shared__ float dis[32];
    __shared__ float ps[256];

    const int t = threadIdx.x;
    const int l15 = t & 15;
    const int quad = t >> 4;

    // k-validity mask for B-operand repacks (k = quad*8+j < 19)
    float km[8];
    #pragma unroll
    for (int j = 0; j < 8; ++j) km[j] = (quad * 8 + j < GN) ? 1.f : 0.f;

    // loop-invariant scatter coords for A staging (e = t + 64*i)
    int rr[6], cc[6];
    #pragma unroll
    for (int i = 0; i < 6; ++i) {
        int e = t + 64 * i;
        rr[i] = e / GN;
        cc[i] = e - rr[i] * GN;
    }

    // ---- weight fragments + biases (once per block) ----
    Frag w1F[4];
    #pragma unroll
    for (int nt = 0; nt < 4; ++nt) {
        int n = nt * 16 + l15;
        #pragma unroll
        for (int p = 0; p < 4; ++p) {
            int k0 = quad * 8 + 2 * p, k1 = k0 + 1;
            float a = (k0 < GN) ? w1_w[n * GN + k0] : 0.f;
            float b = (k1 < GN) ? w1_w[n * GN + k1] : 0.f;
            w1F[nt].i[p] = pkbf(a, b);
        }
    }
    Frag w2F[2][4];
    #pragma unroll
    for (int kt = 0; kt < 2; ++kt)
        #pragma unroll
        for (int nt = 0; nt < 4; ++nt) {
            int n = nt * 16 + l15;
            #pragma unroll
            for (int p = 0; p < 4; ++p) {
                int k = kt * 32 + quad * 8 + 2 * p;
                w2F[kt][nt].i[p] = pkbf(w2_w[n * 64 + k], w2_w[n * 64 + k + 1]);
            }
        }
    float b1v[4], b2v[4];
    #pragma unroll
    for (int nt = 0; nt < 4; ++nt) {
        b1v[nt] = w1_b[nt * 16 + l15];
        b2v[nt] = w2_b[nt * 16 + l15];
    }

    // prologue: prefetch first graph's A into registers
    float pf[6];
    {
        int g0 = blockIdx.x < num_graphs ? blockIdx.x : 0;
        const float* Ag = conn + (size_t)g0 * (GN * GN);
        #pragma unroll
        for (int i = 0; i < 6; ++i) {
            int e = t + 64 * i;
            if (e < GN * GN) pf[i] = Ag[e];
        }
    }

    #pragma unroll 1
    for (int g = blockIdx.x; g < num_graphs; g += gridDim.x) {
        // zero A region: rows 0..31, cols 0..31 (stride 68)
        #pragma unroll
        for (int i = 0; i < 4; ++i) {
            int s = t + 64 * i;          // 256 float4 slots
            int row = s >> 3, c4 = s & 7;
            f4 z = {0.f, 0.f, 0.f, 0.f};
            *(f4*)&S[row * 68 + c4 * 4] = z;
        }
        LWAIT();   // zeros before scatter (same addresses)
        // scatter prefetched A (361 floats)
        #pragma unroll
        for (int i = 0; i < 6; ++i) {
            if (t + 64 * i < GN * GN) S[rr[i] * 68 + cc[i]] = pf[i];
        }
        // issue prefetch for the NEXT graph (stays in flight all pipeline)
        {
            int gn = g + gridDim.x;
            const float* Ag = conn + (size_t)(gn < num_graphs ? gn : g) * (GN * GN);
            #pragma unroll
            for (int i = 0; i < 6; ++i) {
                int e = t + 64 * i;
                if (e < GN * GN) pf[i] = Ag[e];
            }
        }
        LWAIT();   // staging visible

        // degree -> dis (lanes 0..18), zero pad 19..31
        if (t < 32) {
            float dv = 0.f;
            if (t < GN) {
                float d = 1.0f;   // self loop
                #pragma unroll
                for (int c4 = 0; c4 < 8; ++c4) {
                    f4 v = *(f4*)&S[t * 68 + c4 * 4];
                    d += v.x + v.y + v.z + v.w;
                }
                dv = rsqrtf(d);
            }
            dis[t] = dv;
        }
        LWAIT();

        // pack aF (raw A) and anF (normalized adjacency), 2 M-tiles
        float dk[8];
        {
            f4 v0 = *(f4*)&dis[quad * 8];
            f4 v1 = *(f4*)&dis[quad * 8 + 4];
            dk[0]=v0.x; dk[1]=v0.y; dk[2]=v0.z; dk[3]=v0.w;
            dk[4]=v1.x; dk[5]=v1.y; dk[6]=v1.z; dk[7]=v1.w;
        }
        Frag aF[2], anF[2];
        #pragma unroll
        for (int mt = 0; mt < 2; ++mt) {
            int m = l15 + 16 * mt;
            float dm = dis[m];
            f4 v0 = *(f4*)&S[m * 68 + quad * 8];
            f4 v1 = *(f4*)&S[m * 68 + quad * 8 + 4];
            float av[8] = {v0.x, v0.y, v0.z, v0.w, v1.x, v1.y, v1.z, v1.w};
            float an[8];
            #pragma unroll
            for (int j = 0; j < 8; ++j) {
                int k = quad * 8 + j;
                an[j] = (av[j] + (m == k ? 1.f : 0.f)) * dm * dk[j];
            }
            #pragma unroll
            for (int p = 0; p < 4; ++p) {
                aF[mt].i[p]  = pkbf(av[2*p], av[2*p+1]);
                anF[mt].i[p] = pkbf(an[2*p], an[2*p+1]);
            }
        }
        LWAIT();   // A reads done before H1^T overwrites S

        // MFMA1: H1 = A @ W1^T + b1  -> S transposed (S[n*36 + k])
        #pragma unroll
        for (int mt = 0; mt < 2; ++mt)
            #pragma unroll
            for (int nt = 0; nt < 4; ++nt) {
                float bb = b1v[nt];
                f4 c = {bb, bb, bb, bb};
                c = __builtin_amdgcn_mfma_f32_16x16x32_bf16(aF[mt].s, w1F[nt].s, c, 0, 0, 0);
                int col = nt * 16 + l15;
                #pragma unroll
                for (int r = 0; r < 4; ++r)
                    S[col * 36 + (mt * 16 + quad * 4 + r)] = c[r];
            }
        LWAIT();

        // pack H1 as B-op: 2 x b128 per n-tile, mask k>=19
        Frag hF[4];
        #pragma unroll
        for (int nt = 0; nt < 4; ++nt) {
            int n = nt * 16 + l15;
            f4 v0 = *(f4*)&S[n * 36 + quad * 8];
            f4 v1 = *(f4*)&S[n * 36 + quad * 8 + 4];
            float vv[8] = {v0.x, v0.y, v0.z, v0.w, v1.x, v1.y, v1.z, v1.w};
            #pragma unroll
            for (int p = 0; p < 4; ++p)
                hF[nt].i[p] = pkbf(vv[2*p] * km[2*p], vv[2*p+1] * km[2*p+1]);
        }
        LWAIT();   // H1^T reads done

        // MFMA2: X1 = relu(An @ H1) -> S row-major (rows>=19 naturally zero)
        #pragma unroll
        for (int mt = 0; mt < 2; ++mt)
            #pragma unroll
            for (int nt = 0; nt < 4; ++nt) {
                f4 c = {0.f, 0.f, 0.f, 0.f};
                c = __builtin_amdgcn_mfma_f32_16x16x32_bf16(anF[mt].s, hF[nt].s, c, 0, 0, 0);
                int col = nt * 16 + l15;
                #pragma unroll
                for (int r = 0; r < 4; ++r)
                    S[(mt * 16 + quad * 4 + r) * 68 + col] = fmaxf(c[r], 0.f);
            }
        LWAIT();

        // pack X1 as A-op (2 b128 per (mt,kt))
        Frag xF[2][2];
        #pragma unroll
        for (int mt = 0; mt < 2; ++mt) {
            int m = l15 + 16 * mt;
            #pragma unroll
            for (int kt = 0; kt < 2; ++kt) {
                f4 v0 = *(f4*)&S[m * 68 + kt * 32 + quad * 8];
                f4 v1 = *(f4*)&S[m * 68 + kt * 32 + quad * 8 + 4];
                xF[mt][kt].i[0] = pkbf(v0.x, v0.y);
                xF[mt][kt].i[1] = pkbf(v0.z, v0.w);
                xF[mt][kt].i[2] = pkbf(v1.x, v1.y);
                xF[mt][kt].i[3] = pkbf(v1.z, v1.w);
            }
        }
        LWAIT();   // X1 reads done

        // MFMA3: H2 = X1 @ W2^T + b2 -> S transposed
        #pragma unroll
        for (int mt = 0; mt < 2; ++mt)
            #pragma unroll
            for (int nt = 0; nt < 4; ++nt) {
                float bb = b2v[nt];
                f4 c = {bb, bb, bb, bb};
                c = __builtin_amdgcn_mfma_f32_16x16x32_bf16(xF[mt][0].s, w2F[0][nt].s, c, 0, 0, 0);
                c = __builtin_amdgcn_mfma_f32_16x16x32_bf16(xF[mt][1].s, w2F[1][nt].s, c, 0, 0, 0);
                int col = nt * 16 + l15;
                #pragma unroll
                for (int r = 0; r < 4; ++r)
                    S[col * 36 + (mt * 16 + quad * 4 + r)] = c[r];
            }
        LWAIT();

        // pack H2 as B-op
        #pragma unroll
        for (int nt = 0; nt < 4; ++nt) {
            int n = nt * 16 + l15;
            f4 v0 = *(f4*)&S[n * 36 + quad * 8];
            f4 v1 = *(f4*)&S[n * 36 + quad * 8 + 4];
            float vv[8] = {v0.x, v0.y, v0.z, v0.w, v1.x, v1.y, v1.z, v1.w};
            #pragma unroll
            for (int p = 0; p < 4; ++p)
                hF[nt].i[p] = pkbf(vv[2*p] * km[2*p], vv[2*p+1] * km[2*p+1]);
        }

        // MFMA4: X2 = relu(An @ H2); column sums -> emb mean
        float cs[4];
        #pragma unroll
        for (int nt = 0; nt < 4; ++nt) cs[nt] = 0.f;
        #pragma unroll
        for (int mt = 0; mt < 2; ++mt)
            #pragma unroll
            for (int nt = 0; nt < 4; ++nt) {
                f4 c = {0.f, 0.f, 0.f, 0.f};
                c = __builtin_amdgcn_mfma_f32_16x16x32_bf16(anF[mt].s, hF[nt].s, c, 0, 0, 0);
                if (mt == 0) {
                    cs[nt] += fmaxf(c[0], 0.f) + fmaxf(c[1], 0.f)
                            + fmaxf(c[2], 0.f) + fmaxf(c[3], 0.f);
                } else if (quad == 0) {   // rows 16,17,18 valid
                    cs[nt] += fmaxf(c[0], 0.f) + fmaxf(c[1], 0.f) + fmaxf(c[2], 0.f);
                }
            }
        #pragma unroll
        for (int nt = 0; nt < 4; ++nt)
            ps[quad * 64 + nt * 16 + l15] = cs[nt];
        LWAIT();
        float tot = ps[t] + ps[64 + t] + ps[128 + t] + ps[192 + t];
        float mf = (float)mask[g];
        emb[(size_t)g * 64 + t] = tot * (1.f / 19.f) * mf;
        LWAIT();   // ps reads done before next iteration reuses LDS
    }
}

// ---------------------------------------------------------------------------
// Kernel B: FUSED 2-layer LSTM + FC head.  One block per batch element,
// 256 threads; thread tid owns gate-row tid of BOTH layers (wave w = gate
// type, lane l = h-dim).  1-step pipeline skew: iteration t computes layer-0
// gates for step t and layer-1 gates for step t-1 -- two independent
// recurrences share every stall (barrier, gate ds_reads, activation chains),
// and the readlane(h0) broadcasts feed both Whh0 and Wih1 FMAs.
// h0seq never touches HBM.  Raw s_barrier (no vmcnt drain).
// ---------------------------------------------------------------------------
__global__ __launch_bounds__(256, 1) void lstm_fused(
    const float* __restrict__ x,      // (B*T, 64) = emb
    const int*   __restrict__ mask,   // (B, T)
    const float* __restrict__ Wih0, const float* __restrict__ Whh0,
    const float* __restrict__ bih0, const float* __restrict__ bhh0,
    const float* __restrict__ Wih1, const float* __restrict__ Whh1,
    const float* __restrict__ bih1, const float* __restrict__ bhh1,
    const float* __restrict__ fc1_w, const float* __restrict__ fc1_b,
    const float* __restrict__ fc2_w, const float* __restrict__ fc2_b,
    float* __restrict__ out)          // (B, 2)
{
    __shared__ float gs0[2][256];
    __shared__ float gs1[2][256];
    __shared__ int li_s;
    const int tid = threadIdx.x;
    const int w = tid >> 6, l = tid & 63;
    const int b = blockIdx.x;

    // per-thread weight rows: 4 x 64 = 256 VGPRs
    float wi0[64], wh0[64], wi1[64], wh1[64];
    {
        const float4* p0 = (const float4*)(Wih0 + tid * 64);
        const float4* q0 = (const float4*)(Whh0 + tid * 64);
        const float4* p1 = (const float4*)(Wih1 + tid * 64);
        const float4* q1 = (const float4*)(Whh1 + tid * 64);
        #pragma unroll
        for (int j = 0; j < 16; ++j) {
            ((float4*)wi0)[j] = p0[j];
            ((float4*)wh0)[j] = q0[j];
            ((float4*)wi1)[j] = p1[j];
            ((float4*)wh1)[j] = q1[j];
        }
    }
    const float bias0 = bih0[tid] + bhh0[tid];
    const float bias1 = bih1[tid] + bhh1[tid];

    // last_idx = clip(sum(mask)-1, 0, T-1)
    gs0[0][tid] = (float)mask[b * TT + tid];
    __syncthreads();
    if (tid == 0) {
        float s = 0.f;
        for (int t = 0; t < TT; ++t) s += gs0[0][t];
        int li = (int)s - 1;
        li = li < 0 ? 0 : (li > TT - 1 ? TT - 1 : li);
        li_s = li;
    }
    __syncthreads();
    const int lastidx = li_s;

    const float* __restrict__ xb = x + (size_t)b * TT * 64;

    // x-contribution for layer-0 step 0
    float xc0;
    {
        float n0 = 0.f, n1 = 0.f, n2 = 0.f, n3 = 0.f;
        #pragma unroll
        for (int j = 0; j < 64; j += 4) {
            n0 = fmaf(xb[j],     wi0[j],     n0);
            n1 = fmaf(xb[j + 1], wi0[j + 1], n1);
            n2 = fmaf(xb[j + 2], wi0[j + 2], n2);
            n3 = fmaf(xb[j + 3], wi0[j + 3], n3);
        }
        xc0 = (n0 + n1) + (n2 + n3);
    }

    float h0 = 0.f, c0 = 0.f;   // layer-0 state (dim l, replicated per wave)
    float h1 = 0.f, c1 = 0.f;   // layer-1 state
    float hl = 0.f;             // h1 at lastidx

    #pragma unroll 1
    for (int t = 0; t <= TT; ++t) {
        const bool do0 = (t < TT);
        const bool do1 = (t >= 1);

        // issue raw loads of emb row t+1 (consumed at iteration end)
        f4 xr[16];
        if (do0) {
            const f4* __restrict__ ern =
                (const f4*)(xb + (t + 1 < TT ? t + 1 : TT - 1) * 64);
            #pragma unroll
            for (int k = 0; k < 16; ++k) xr[k] = ern[k];
        }

        // recurrent FMAs: layer0 gates(t) and layer1 gates(t-1).
        // rl(h0,·) feeds BOTH wh0 (l0 recurrent) and wi1 (l1 input).
        float a0 = bias0 + xc0, a1 = 0.f, a2 = 0.f, a3 = 0.f;
        float p0 = bias1, p1 = 0.f, p2 = 0.f, p3 = 0.f;   // wi1 · h0
        float q0 = 0.f, q1 = 0.f, q2 = 0.f, q3 = 0.f;     // wh1 · h1
        #pragma unroll
        for (int j = 0; j < 64; j += 4) {
            float h0a = rl(h0, j),     h0b = rl(h0, j + 1);
            float h0c = rl(h0, j + 2), h0d = rl(h0, j + 3);
            a0 = fmaf(h0a, wh0[j],     a0);
            a1 = fmaf(h0b, wh0[j + 1], a1);
            a2 = fmaf(h0c, wh0[j + 2], a2);
            a3 = fmaf(h0d, wh0[j + 3], a3);
            p0 = fmaf(h0a, wi1[j],     p0);
            p1 = fmaf(h0b, wi1[j + 1], p1);
            p2 = fmaf(h0c, wi1[j + 2], p2);
            p3 = fmaf(h0d, wi1[j + 3], p3);
            float h1a = rl(h1, j),     h1b = rl(h1, j + 1);
            float h1c = rl(h1, j + 2), h1d = rl(h1, j + 3);
            q0 = fmaf(h1a, wh1[j],     q0);
            q1 = fmaf(h1b, wh1[j + 1], q1);
            q2 = fmaf(h1c, wh1[j + 2], q2);
            q3 = fmaf(h1d, wh1[j + 3], q3);
        }
        if (do0) gs0[t & 1][tid] = (a0 + a1) + (a2 + a3);
        if (do1) gs1[t & 1][tid] = ((p0 + p1) + (p2 + p3)) + ((q0 + q1) + (q2 + q3));
        WGBAR();

        if (do0) {
            const float* gp = gs0[t & 1];
            float gi = gp[l], gf = gp[64 + l], gg = gp[128 + l], go = gp[192 + l];
            c0 = sigm(gf) * c0 + sigm(gi) * tanha(gg);
            h0 = sigm(go) * tanha(c0);
        }
        if (do1) {
            const float* gp = gs1[t & 1];
            float gi = gp[l], gf = gp[64 + l], gg = gp[128 + l], go = gp[192 + l];
            c1 = sigm(gf) * c1 + sigm(gi) * tanha(gg);
            h1 = sigm(go) * tanha(c1);
            if (t - 1 == lastidx) hl = h1;
        }

        // x-contribution for layer-0 step t+1 from prefetched regs
        if (do0) {
            float n0 = 0.f, n1 = 0.f, n2 = 0.f, n3 = 0.f;
            #pragma unroll
            for (int k = 0; k < 16; ++k) {
                f4 v = xr[k];
                n0 = fmaf(v.x, wi0[4*k],     n0);
                n1 = fmaf(v.y, wi0[4*k + 1], n1);
                n2 = fmaf(v.z, wi0[4*k + 2], n2);
                n3 = fmaf(v.w, wi0[4*k + 3], n3);
            }
            xc0 = (n0 + n1) + (n2 + n3);
        }
    }

    // head: fc1 (64->32) relu, fc2 (32->2); wave 0 only
    __syncthreads();
    if (w == 0 && l < 32) {
        float acc = fc1_b[l];
        const float* fw = fc1_w + l * 64;
        #pragma unroll
        for (int j = 0; j < 64; ++j)
            acc = fmaf(fw[j], rl(hl, j), acc);
        gs0[0][l] = fmaxf(acc, 0.f);
    }
    __syncthreads();
    if (w == 0 && l < 2) {
        float acc = fc2_b[l];
        #pragma unroll
        for (int j = 0; j < 32; ++j)
            acc = fmaf(fc2_w[l * 32 + j], gs0[0][j], acc);
        out[b * 2 + l] = acc;
    }
}

// ---------------------------------------------------------------------------
extern "C" void kernel_launch(void* const* d_in, const int* in_sizes, int n_in,
                              void* d_out, int out_size, void* d_ws, size_t ws_size,
                              hipStream_t stream)
{
    const float* conn  = (const float*)d_in[0];
    const int*   mask  = (const int*)  d_in[1];
    const float* w1_w  = (const float*)d_in[2];
    const float* w1_b  = (const float*)d_in[3];
    const float* w2_w  = (const float*)d_in[4];
    const float* w2_b  = (const float*)d_in[5];
    const float* Wih0  = (const float*)d_in[6];
    const float* Whh0  = (const float*)d_in[7];
    const float* bih0  = (const float*)d_in[8];
    const float* bhh0  = (const float*)d_in[9];
    const float* Wih1  = (const float*)d_in[10];
    const float* Whh1  = (const float*)d_in[11];
    const float* bih1  = (const float*)d_in[12];
    const float* bhh1  = (const float*)d_in[13];
    const float* fc1_w = (const float*)d_in[14];
    const float* fc1_b = (const float*)d_in[15];
    const float* fc2_w = (const float*)d_in[16];
    const float* fc2_b = (const float*)d_in[17];

    float* out = (float*)d_out;
    float* emb = (float*)d_ws;            // 16.8 MB

    const int num_graphs = BB * TT;

    encoder_mfma<<<8192, 64, 0, stream>>>(
        conn, mask, w1_w, w1_b, w2_w, w2_b, emb, num_graphs);

    lstm_fused<<<BB, 256, 0, stream>>>(
        emb, mask, Wih0, Whh0, bih0, bhh0, Wih1, Whh1, bih1, bhh1,
        fc1_w, fc1_b, fc2_w, fc2_b, out);
}